// Round 9
// baseline (1022.012 us; speedup 1.0000x reference)
//
#include <hip/hip_runtime.h>
#include <hip/hip_bf16.h>
#include <cstddef>

// Problem constants (match reference)
constexpr int B_SZ  = 2;
constexpr int LSEQ  = 2048;
constexpr int DIM   = 768;
constexpr int H_DIM = 1536;
constexpr int DST   = 16;      // D_STATE
constexpr int KW    = 4;       // conv kernel width
constexpr int MROWS = B_SZ * LSEQ;        // 4096
constexpr int HS    = H_DIM * DST;        // 24576

// chunked scan config
constexpr int CCH  = 16;                  // chunks
constexpr int CLEN = LSEQ / CCH;          // 128

using short8 = __attribute__((ext_vector_type(8))) short;
using f32x4  = __attribute__((ext_vector_type(4))) float;

// fp32 -> bf16 (RNE) and back, via bit ops (inputs are finite/well-scaled)
__device__ __forceinline__ short f2bf(float v) {
    union { float f; unsigned u; } x; x.f = v;
    unsigned r = (x.u + 0x7FFFu + ((x.u >> 16) & 1u)) >> 16;
    return (short)r;
}
__device__ __forceinline__ float bf2f(short s) {
    union { unsigned u; float f; } x; x.u = ((unsigned)(unsigned short)s) << 16;
    return x.f;
}

// ===========================================================================
// Weight transpose + bf16x2 split: W[K][N] fp32 -> Wh[N][K], Wl[N][K] bf16.
// ===========================================================================
__global__ __launch_bounds__(256) void wsplit_k(
    const float* __restrict__ W, unsigned short* __restrict__ Wh,
    unsigned short* __restrict__ Wl, int K, int N)
{
    __shared__ float t[32][33];
    const int k0 = blockIdx.x * 32, n0 = blockIdx.y * 32;
    const int r = threadIdx.x >> 5, c = threadIdx.x & 31;
#pragma unroll
    for (int p = 0; p < 4; ++p)
        t[r + p * 8][c] = W[(size_t)(k0 + r + p * 8) * N + n0 + c];
    __syncthreads();
#pragma unroll
    for (int p = 0; p < 4; ++p) {
        int rr = r + p * 8;                       // n-offset in tile
        float v = t[c][rr];                       // = W[k0+c][n0+rr]
        short hi = f2bf(v);
        short lo = f2bf(v - bf2f(hi));
        size_t o = (size_t)(n0 + rr) * K + k0 + c;
        Wh[o] = (unsigned short)hi;
        Wl[o] = (unsigned short)lo;
    }
}

// ===========================================================================
// Elementwise bf16x2 split of x (activations): row-major [M][K] kept.
// ===========================================================================
__global__ __launch_bounds__(256) void xsplit_k(
    const float* __restrict__ X, unsigned short* __restrict__ Xh,
    unsigned short* __restrict__ Xl, size_t n8)
{
    size_t g = (size_t)blockIdx.x * 256 + threadIdx.x;
    if (g >= n8) return;
    const float* xp = X + g * 8;
    float v[8];
    *reinterpret_cast<float4*>(&v[0]) = *reinterpret_cast<const float4*>(xp);
    *reinterpret_cast<float4*>(&v[4]) = *reinterpret_cast<const float4*>(xp + 4);
    short h[8], l[8];
#pragma unroll
    for (int i = 0; i < 8; ++i) {
        h[i] = f2bf(v[i]);
        l[i] = f2bf(v[i] - bf2f(h[i]));
    }
    *reinterpret_cast<short8*>(Xh + g * 8) = *reinterpret_cast<short8*>(&h[0]);
    *reinterpret_cast<short8*>(Xl + g * 8) = *reinterpret_cast<short8*>(&l[0]);
}

// ===========================================================================
// bf16x2 emulated-fp32 GEMM, all operands PRE-SPLIT bf16 (staging = copies).
// C[M,N] = epi(A @ B^T + bias); A as Ah/Al [M][K], B as Bh/Bl [N][K].
// a*b ~= ah*bh + ah*bl + al*bh  (drop ll: rel err ~1e-5).
// Tile 128(M) x 64(N), BK=32, 128 thr = 2 waves; wave w owns rows w*64..+63
// (4x4 frags of mfma_f32_16x16x32_bf16). Grid for N=1536: 24x32=768 blocks
// -> 3 blocks/CU balanced (round-5/7 lesson: occupancy first).
// C/D layout: col=lane&15, row=(lane>>4)*4+reg [m89]. LDS rows stride 40
// shorts (80B: 16B-aligned, frag reads spread banks, <=2-way alias).
// ===========================================================================
template <int EPI>
__global__ __launch_bounds__(128) void gemm_bf(
    const unsigned short* __restrict__ Ahp, const unsigned short* __restrict__ Alp,
    const unsigned short* __restrict__ Bhp, const unsigned short* __restrict__ Blp,
    const float* __restrict__ bias, const float* __restrict__ extra,
    float* __restrict__ C, int M, int N, int K)
{
    constexpr int SK = 40;
    __shared__ short Ah[128 * SK], Al[128 * SK];
    __shared__ short Bh[64 * SK],  Bl[64 * SK];

    const int tid  = threadIdx.x;                 // 0..127
    const int n0   = blockIdx.x * 64, m0 = blockIdx.y * 128;
    const int wave = tid >> 6, lane = tid & 63;
    const int lr   = lane & 15, kg = lane >> 4;

    f32x4 acc[4][4] = {};

    for (int k0 = 0; k0 < K; k0 += 32) {
        // ---- stage A: thread t copies row t (hi & lo), 32 shorts each
        {
            const unsigned short* ah = Ahp + (size_t)(m0 + tid) * K + k0;
            const unsigned short* al = Alp + (size_t)(m0 + tid) * K + k0;
            int ab = tid * SK;
#pragma unroll
            for (int i = 0; i < 4; ++i) {
                *reinterpret_cast<short8*>(&Ah[ab + 8 * i]) =
                    *reinterpret_cast<const short8*>(ah + 8 * i);
                *reinterpret_cast<short8*>(&Al[ab + 8 * i]) =
                    *reinterpret_cast<const short8*>(al + 8 * i);
            }
        }
        // ---- stage B: threads 0-63 copy Bh row t, 64-127 copy Bl row t-64
        {
            int brow = tid & 63;
            const unsigned short* bp =
                (tid < 64 ? Bhp : Blp) + (size_t)(n0 + brow) * K + k0;
            short* bd = (tid < 64 ? Bh : Bl) + brow * SK;
#pragma unroll
            for (int i = 0; i < 4; ++i)
                *reinterpret_cast<short8*>(&bd[8 * i]) =
                    *reinterpret_cast<const short8*>(bp + 8 * i);
        }
        __syncthreads();

        short8 fa_h[4], fa_l[4], fb_h[4], fb_l[4];
#pragma unroll
        for (int f = 0; f < 4; ++f) {
            int aoff = (wave * 64 + f * 16 + lr) * SK + kg * 8;
            int boff = (f * 16 + lr) * SK + kg * 8;
            fa_h[f] = *reinterpret_cast<const short8*>(&Ah[aoff]);
            fa_l[f] = *reinterpret_cast<const short8*>(&Al[aoff]);
            fb_h[f] = *reinterpret_cast<const short8*>(&Bh[boff]);
            fb_l[f] = *reinterpret_cast<const short8*>(&Bl[boff]);
        }
        // 3 passes; same-acc MFMAs spaced 16 apart (latency hiding)
#pragma unroll
        for (int mf = 0; mf < 4; ++mf)
#pragma unroll
            for (int nf = 0; nf < 4; ++nf)
                acc[mf][nf] = __builtin_amdgcn_mfma_f32_16x16x32_bf16(
                    fa_h[mf], fb_h[nf], acc[mf][nf], 0, 0, 0);
#pragma unroll
        for (int mf = 0; mf < 4; ++mf)
#pragma unroll
            for (int nf = 0; nf < 4; ++nf)
                acc[mf][nf] = __builtin_amdgcn_mfma_f32_16x16x32_bf16(
                    fa_h[mf], fb_l[nf], acc[mf][nf], 0, 0, 0);
#pragma unroll
        for (int mf = 0; mf < 4; ++mf)
#pragma unroll
            for (int nf = 0; nf < 4; ++nf)
                acc[mf][nf] = __builtin_amdgcn_mfma_f32_16x16x32_bf16(
                    fa_l[mf], fb_h[nf], acc[mf][nf], 0, 0, 0);
        __syncthreads();
    }

    // ---- epilogue
    float bv[4], ev[4];
#pragma unroll
    for (int nf = 0; nf < 4; ++nf) {
        int col = n0 + nf * 16 + lr;
        bv[nf] = bias[col];
        ev[nf] = (EPI == 2) ? extra[col] : 0.f;
    }
#pragma unroll
    for (int mf = 0; mf < 4; ++mf)
#pragma unroll
        for (int nf = 0; nf < 4; ++nf) {
            int col = n0 + nf * 16 + lr;
#pragma unroll
            for (int r = 0; r < 4; ++r) {
                int mrow = m0 + wave * 64 + mf * 16 + kg * 4 + r;
                float v = acc[mf][nf][r] + bv[nf];
                if (EPI == 1) v = v / (1.f + expf(-v));            // silu
                if (EPI == 2) {                                    // softplus(extra+v)
                    float t2 = ev[nf] + v;
                    v = fmaxf(t2, 0.f) + log1pf(expf(-fabsf(t2)));
                }
                C[(size_t)mrow * N + col] = v;
            }
        }
}

// ---------------------------------------------------------------------------
// depthwise causal conv (K=4) + bias + silu.
// Outputs: a fp32 (for bm/scans), ah/al bf16x2 (for delta-GEMM),
// p=a*g split ph/pl (for output-GEMM), trim = a[...,1:] (final output).
// ---------------------------------------------------------------------------
__global__ __launch_bounds__(256) void conv_k(
    const float* __restrict__ apre, const float* __restrict__ cw,
    const float* __restrict__ cb, const float* __restrict__ g,
    float* __restrict__ aout,
    unsigned short* __restrict__ ah, unsigned short* __restrict__ al,
    unsigned short* __restrict__ ph, unsigned short* __restrict__ pl,
    float* __restrict__ trim)
{
    int idx = blockIdx.x * 256 + threadIdx.x;          // (b*L + t)*H + d
    int d  = idx % H_DIM;
    int bt = idx / H_DIM;
    int t  = bt % LSEQ;

    float4 w = *reinterpret_cast<const float4*>(cw + (size_t)d * KW);
    float acc = cb[d];
    if (t >= KW - 1) {
        const float* base = apre + (size_t)(bt - 3) * H_DIM + d;
        acc += base[0] * w.x;
        acc += base[H_DIM] * w.y;
        acc += base[2 * H_DIM] * w.z;
        acc += base[3 * H_DIM] * w.w;
    } else {
        const float* wp = reinterpret_cast<const float*>(&w);
#pragma unroll
        for (int j = 0; j < KW; ++j) {
            int tt = t + j - (KW - 1);
            if (tt >= 0) acc += apre[(size_t)(bt + j - 3) * H_DIM + d] * wp[j];
        }
    }
    float sv = acc / (1.f + expf(-acc));               // silu
    aout[idx] = sv;
    short h = f2bf(sv);
    ah[idx] = (unsigned short)h;
    al[idx] = (unsigned short)f2bf(sv - bf2f(h));
    float pv = sv * g[idx];
    short hp = f2bf(pv);
    ph[idx] = (unsigned short)hp;
    pl[idx] = (unsigned short)f2bf(pv - bf2f(hp));
    if (d >= 1)
        __builtin_nontemporal_store(sv, &trim[(size_t)bt * (H_DIM - 1) + d - 1]);
}

// ---------------------------------------------------------------------------
// Bm = a @ WB + bB   (skinny N=16)
// ---------------------------------------------------------------------------
__global__ __launch_bounds__(256) void bm_k(
    const float* __restrict__ a, const float* __restrict__ WB,
    const float* __restrict__ bB, float* __restrict__ Bm)
{
    int g = blockIdx.x * 256 + threadIdx.x;            // row*16 + n
    int row = g >> 4, n = g & 15;
    const float* ar = a + (size_t)row * H_DIM;
    float a0 = 0.f, a1 = 0.f, a2 = 0.f, a3 = 0.f;
    for (int k = 0; k < H_DIM; k += 4) {
        a0 = fmaf(ar[k],     WB[(size_t)(k)*DST + n],     a0);
        a1 = fmaf(ar[k + 1], WB[(size_t)(k + 1)*DST + n], a1);
        a2 = fmaf(ar[k + 2], WB[(size_t)(k + 2)*DST + n], a2);
        a3 = fmaf(ar[k + 3], WB[(size_t)(k + 3)*DST + n], a3);
    }
    Bm[g] = bB[n] + ((a0 + a1) + (a2 + a3));
}

// ---------------------------------------------------------------------------
// chunked selective scan:  h_t = (e^{-A} * delta_t) * h_{t-1} + Bm_t*delta_t*a_t
// Intermediates hend/P/Hinit laid out [(b*CCH + c)*HS + ds] (coalesced in ds).
// ---------------------------------------------------------------------------
__global__ __launch_bounds__(256) void scan_a(
    const float* __restrict__ delta, const float* __restrict__ a,
    const float* __restrict__ Bm, const float* __restrict__ A,
    float* __restrict__ hend, float* __restrict__ Pout)
{
    int gtid = blockIdx.x * 256 + threadIdx.x;         // B*CCH*HS
    int ds = gtid % HS;
    int bc = gtid / HS;
    int c = bc % CCH, b = bc / CCH;
    int d = ds >> 4, s = ds & 15;

    float eA = expf(-A[ds]);
    float h = 0.f, P = 1.f;
    int bt0 = b * LSEQ + c * CLEN;
#pragma unroll 4
    for (int i = 0; i < CLEN; ++i) {
        int bt = bt0 + i;
        size_t ix = (size_t)bt * H_DIM + d;
        float dl = delta[ix];
        float av = a[ix];
        float bm = Bm[(size_t)bt * DST + s];
        float at = eA * dl;
        h = fmaf(at, h, bm * dl * av);
        P *= at;
    }
    size_t o = ((size_t)b * CCH + c) * HS + ds;
    hend[o] = h;
    Pout[o] = P;
}

__global__ __launch_bounds__(256) void scan_b(
    const float* __restrict__ hend, const float* __restrict__ P,
    float* __restrict__ Hinit)
{
    int gtid = blockIdx.x * 256 + threadIdx.x;         // B*HS
    int ds = gtid % HS;
    int b  = gtid / HS;
    float Hc = 0.f;
    for (int c = 0; c < CCH; ++c) {
        size_t o = ((size_t)b * CCH + c) * HS + ds;
        Hinit[o] = Hc;
        Hc = hend[o] + P[o] * Hc;
    }
}

__global__ __launch_bounds__(256) void scan_c(
    const float* __restrict__ delta, const float* __restrict__ a,
    const float* __restrict__ Bm, const float* __restrict__ A,
    const float* __restrict__ Hinit, float* __restrict__ hid)
{
    int gtid = blockIdx.x * 256 + threadIdx.x;
    int ds = gtid % HS;
    int bc = gtid / HS;
    int c = bc % CCH, b = bc / CCH;
    int d = ds >> 4, s = ds & 15;

    float eA = expf(-A[ds]);
    float h = Hinit[((size_t)b * CCH + c) * HS + ds];
    int bt0 = b * LSEQ + c * CLEN;
#pragma unroll 4
    for (int i = 0; i < CLEN; ++i) {
        int bt = bt0 + i;
        size_t ix = (size_t)bt * H_DIM + d;
        float dl = delta[ix];
        float av = a[ix];
        float bm = Bm[(size_t)bt * DST + s];
        float at = eA * dl;
        h = fmaf(at, h, bm * dl * av);
        // hid is written once, never re-read on device: stream past the caches
        __builtin_nontemporal_store(h, &hid[(size_t)bt * HS + ds]);
    }
}

// ---------------------------------------------------------------------------
extern "C" void kernel_launch(void* const* d_in, const int* in_sizes, int n_in,
                              void* d_out, int out_size, void* d_ws, size_t ws_size,
                              hipStream_t stream)
{
    const float* x      = (const float*)d_in[0];
    const float* W1     = (const float*)d_in[1];
    const float* b1     = (const float*)d_in[2];
    const float* W2     = (const float*)d_in[3];
    const float* b2     = (const float*)d_in[4];
    const float* conv_w = (const float*)d_in[5];
    const float* conv_b = (const float*)d_in[6];
    const float* Wf     = (const float*)d_in[7];
    const float* bf     = (const float*)d_in[8];
    const float* A      = (const float*)d_in[9];
    const float* WB     = (const float*)d_in[10];
    const float* bB     = (const float*)d_in[11];
    // d_in[12] = WC, d_in[13] = bC : unused by the reference's returned outputs
    const float* WD     = (const float*)d_in[14];
    const float* bD     = (const float*)d_in[15];
    const float* Dvec   = (const float*)d_in[16];

    float* out = (float*)d_out;
    // output layout: [output 4096*768][hid 4096*24576][trim 4096*1535]
    constexpr size_t OUT_HID  = (size_t)MROWS * DIM;
    constexpr size_t OUT_TRIM = OUT_HID + (size_t)MROWS * HS;
    float* out_y    = out;
    float* out_hid  = out + OUT_HID;
    float* out_trim = out + OUT_TRIM;

    // scratch inside the (not-yet-written) hid region of d_out (402 MB);
    // everything here is dead before scan_c overwrites hid.
    constexpr size_t MH = (size_t)MROWS * H_DIM;                   // 6,291,456
    constexpr size_t MD = (size_t)MROWS * DIM;                     // 3,145,728
    float* a_pre = out_hid;                                        // [MH] fp32
    float* g     = out_hid + MH;                                   // [MH] fp32
    unsigned short* wsp = (unsigned short*)(out_hid + 2 * MH);
    constexpr size_t WSMALL = (size_t)H_DIM * DIM;                 // 1,179,648
    constexpr size_t WBIG   = (size_t)H_DIM * H_DIM;               // 2,359,296
    unsigned short* W1h = wsp;            unsigned short* W1l = W1h + WSMALL;
    unsigned short* W2h = W1l + WSMALL;   unsigned short* W2l = W2h + WSMALL;
    unsigned short* WDh = W2l + WSMALL;   unsigned short* WDl = WDh + WBIG;
    unsigned short* Wfh = WDl + WBIG;     unsigned short* Wfl = Wfh + WSMALL;
    unsigned short* xh  = Wfl + WSMALL;   unsigned short* xl  = xh + MD;
    unsigned short* ah  = xl + MD;        unsigned short* al  = ah + MH;
    unsigned short* ph  = al + MH;        unsigned short* pl  = ph + MH;
    // total scratch ~137 MB < 402 MB hid region.

    // workspace layout (floats): a(6.29M) delta(6.29M) Bm(64K) hend/P/Hinit
    float* ws      = (float*)d_ws;
    float* a_ws    = ws;
    float* delta   = a_ws  + MH;
    float* Bm      = delta + MH;
    float* hend    = Bm    + (size_t)MROWS * DST;
    float* Pprod   = hend  + (size_t)B_SZ * HS * CCH;
    float* Hinit   = Pprod + (size_t)B_SZ * HS * CCH;

    dim3 blk(256);
    dim3 gblk(128);

    // 0) operand prep: weight transpose+split, x split
    wsplit_k<<<dim3(DIM / 32, H_DIM / 32), blk, 0, stream>>>(W1, W1h, W1l, DIM, H_DIM);
    wsplit_k<<<dim3(DIM / 32, H_DIM / 32), blk, 0, stream>>>(W2, W2h, W2l, DIM, H_DIM);
    wsplit_k<<<dim3(H_DIM / 32, H_DIM / 32), blk, 0, stream>>>(WD, WDh, WDl, H_DIM, H_DIM);
    wsplit_k<<<dim3(H_DIM / 32, DIM / 32), blk, 0, stream>>>(Wf, Wfh, Wfl, H_DIM, DIM);
    xsplit_k<<<(unsigned)((MD / 8 + 255) / 256), blk, 0, stream>>>(x, xh, xl, MD / 8);

    // 1) a_pre = x@W1 + b1            [4096 x 1536, K=768]  grid 24x32
    gemm_bf<0><<<dim3(H_DIM / 64, MROWS / 128), gblk, 0, stream>>>(
        xh, xl, W1h, W1l, b1, nullptr, a_pre, MROWS, H_DIM, DIM);
    // 2) g = silu(x@W2 + b2)
    gemm_bf<1><<<dim3(H_DIM / 64, MROWS / 128), gblk, 0, stream>>>(
        xh, xl, W2h, W2l, b2, nullptr, g, MROWS, H_DIM, DIM);
    // 3) conv -> a (fp32 + bf16x2) and p = a*g (bf16x2), trim output
    conv_k<<<(MROWS * H_DIM) / 256, blk, 0, stream>>>(
        a_pre, conv_w, conv_b, g, a_ws, ah, al, ph, pl, out_trim);
    // 4) delta = softplus(Dvec + a@WD + bD)   [4096 x 1536, K=1536]
    gemm_bf<2><<<dim3(H_DIM / 64, MROWS / 128), gblk, 0, stream>>>(
        ah, al, WDh, WDl, bD, Dvec, delta, MROWS, H_DIM, H_DIM);
    // 5) Bm = a@WB + bB
    bm_k<<<(MROWS * DST) / 256, blk, 0, stream>>>(a_ws, WB, bB, Bm);
    // 6) output = (a*g)@Wf + bf  [4096 x 768, K=1536]  grid 12x32
    gemm_bf<0><<<dim3(DIM / 64, MROWS / 128), gblk, 0, stream>>>(
        ph, pl, Wfh, Wfl, bf, nullptr, out_y, MROWS, DIM, H_DIM);
    // 7-9) chunked selective scan -> hid
    scan_a<<<(B_SZ * CCH * HS) / 256, blk, 0, stream>>>(delta, a_ws, Bm, A, hend, Pprod);
    scan_b<<<(B_SZ * HS) / 256, blk, 0, stream>>>(hend, Pprod, Hinit);
    scan_c<<<(B_SZ * CCH * HS) / 256, blk, 0, stream>>>(delta, a_ws, Bm, A, Hinit, out_hid);
}

// Round 11
// 998.512 us; speedup vs baseline: 1.0235x; 1.0235x over previous
//
#include <hip/hip_runtime.h>
#include <hip/hip_bf16.h>
#include <cstddef>

// Problem constants (match reference)
constexpr int B_SZ  = 2;
constexpr int LSEQ  = 2048;
constexpr int DIM   = 768;
constexpr int H_DIM = 1536;
constexpr int DST   = 16;      // D_STATE
constexpr int KW    = 4;       // conv kernel width
constexpr int MROWS = B_SZ * LSEQ;        // 4096
constexpr int HS    = H_DIM * DST;        // 24576

// chunked scan config
constexpr int CCH  = 16;                  // chunks
constexpr int CLEN = LSEQ / CCH;          // 128

using short8 = __attribute__((ext_vector_type(8))) short;
using f32x4  = __attribute__((ext_vector_type(4))) float;

// fp32 -> bf16 (RNE) and back, via bit ops (inputs are finite/well-scaled)
__device__ __forceinline__ short f2bf(float v) {
    union { float f; unsigned u; } x; x.f = v;
    unsigned r = (x.u + 0x7FFFu + ((x.u >> 16) & 1u)) >> 16;
    return (short)r;
}
__device__ __forceinline__ float bf2f(short s) {
    union { unsigned u; float f; } x; x.u = ((unsigned)(unsigned short)s) << 16;
    return x.f;
}

// ===========================================================================
// Weight transpose + bf16x2 split: W[K][N] fp32 -> Wh[N][K], Wl[N][K] bf16.
// ===========================================================================
__global__ __launch_bounds__(256) void wsplit_k(
    const float* __restrict__ W, unsigned short* __restrict__ Wh,
    unsigned short* __restrict__ Wl, int K, int N)
{
    __shared__ float t[32][33];
    const int k0 = blockIdx.x * 32, n0 = blockIdx.y * 32;
    const int r = threadIdx.x >> 5, c = threadIdx.x & 31;
#pragma unroll
    for (int p = 0; p < 4; ++p)
        t[r + p * 8][c] = W[(size_t)(k0 + r + p * 8) * N + n0 + c];
    __syncthreads();
#pragma unroll
    for (int p = 0; p < 4; ++p) {
        int rr = r + p * 8;                       // n-offset in tile
        float v = t[c][rr];                       // = W[k0+c][n0+rr]
        short hi = f2bf(v);
        short lo = f2bf(v - bf2f(hi));
        size_t o = (size_t)(n0 + rr) * K + k0 + c;
        Wh[o] = (unsigned short)hi;
        Wl[o] = (unsigned short)lo;
    }
}

// ===========================================================================
// Elementwise bf16x2 split of x (activations): row-major [M][K] kept.
// ===========================================================================
__global__ __launch_bounds__(256) void xsplit_k(
    const float* __restrict__ X, unsigned short* __restrict__ Xh,
    unsigned short* __restrict__ Xl, size_t n8)
{
    size_t g = (size_t)blockIdx.x * 256 + threadIdx.x;
    if (g >= n8) return;
    const float* xp = X + g * 8;
    float v[8];
    *reinterpret_cast<float4*>(&v[0]) = *reinterpret_cast<const float4*>(xp);
    *reinterpret_cast<float4*>(&v[4]) = *reinterpret_cast<const float4*>(xp + 4);
    short h[8], l[8];
#pragma unroll
    for (int i = 0; i < 8; ++i) {
        h[i] = f2bf(v[i]);
        l[i] = f2bf(v[i] - bf2f(h[i]));
    }
    *reinterpret_cast<short8*>(Xh + g * 8) = *reinterpret_cast<short8*>(&h[0]);
    *reinterpret_cast<short8*>(Xl + g * 8) = *reinterpret_cast<short8*>(&l[0]);
}

// ===========================================================================
// Register-direct bf16x2 GEMM: NO LDS, NO barriers.
// Round-9 PMC-derived diagnosis: the LDS-staged variant was ~6x DS-pipe-bound
// (2016 DS-cyc vs 349 MFMA-cyc per CU per K-step). Both operands are L2/L3-
// resident (B <= 9.4MB reused 32-64x; A re-read 24x via L3), and fragments
// are 16B-contiguous in [row][K] bf16 layout -> each lane global_load_dwordx4's
// its fragment directly. Per wave per K-step: 16 loads feed 48 MFMAs.
// One wave per block (64 thr) computes a 64x64 output tile (4x4 frags of
// mfma_f32_16x16x32_bf16). C/D layout: col=lane&15, row=(lane>>4)*4+reg [m89].
// A-frag: row = m0+f*16+(lane&15), k = k0+(lane>>4)*8 (+0..7). Same for B.
// a*b ~= ah*bh + ah*bl + al*bh (drop ll; validated absmax 2.4e-4 in r7/r9).
// ===========================================================================
template <int EPI>
__global__ __launch_bounds__(64) void gemm_reg(
    const unsigned short* __restrict__ Ahp, const unsigned short* __restrict__ Alp,
    const unsigned short* __restrict__ Bhp, const unsigned short* __restrict__ Blp,
    const float* __restrict__ bias, const float* __restrict__ extra,
    float* __restrict__ C, int M, int N, int K)
{
    const int lane = threadIdx.x;                 // 0..63
    const int n0 = blockIdx.x * 64, m0 = blockIdx.y * 64;
    const int lr = lane & 15, kg = lane >> 4;

    // per-fragment base offsets (k advances by +32 per step)
    size_t aoff[4], boff[4];
#pragma unroll
    for (int f = 0; f < 4; ++f) {
        aoff[f] = (size_t)(m0 + f * 16 + lr) * K + kg * 8;
        boff[f] = (size_t)(n0 + f * 16 + lr) * K + kg * 8;
    }

    f32x4 acc[4][4] = {};

    for (int k0 = 0; k0 < K; k0 += 32) {
        short8 fa_h[4], fa_l[4], fb_h[4], fb_l[4];
#pragma unroll
        for (int f = 0; f < 4; ++f) {
            fa_h[f] = *reinterpret_cast<const short8*>(Ahp + aoff[f] + k0);
            fa_l[f] = *reinterpret_cast<const short8*>(Alp + aoff[f] + k0);
            fb_h[f] = *reinterpret_cast<const short8*>(Bhp + boff[f] + k0);
            fb_l[f] = *reinterpret_cast<const short8*>(Blp + boff[f] + k0);
        }
        // 3 passes; same-acc MFMAs spaced 16 apart (latency hiding)
#pragma unroll
        for (int mf = 0; mf < 4; ++mf)
#pragma unroll
            for (int nf = 0; nf < 4; ++nf)
                acc[mf][nf] = __builtin_amdgcn_mfma_f32_16x16x32_bf16(
                    fa_h[mf], fb_h[nf], acc[mf][nf], 0, 0, 0);
#pragma unroll
        for (int mf = 0; mf < 4; ++mf)
#pragma unroll
            for (int nf = 0; nf < 4; ++nf)
                acc[mf][nf] = __builtin_amdgcn_mfma_f32_16x16x32_bf16(
                    fa_h[mf], fb_l[nf], acc[mf][nf], 0, 0, 0);
#pragma unroll
        for (int mf = 0; mf < 4; ++mf)
#pragma unroll
            for (int nf = 0; nf < 4; ++nf)
                acc[mf][nf] = __builtin_amdgcn_mfma_f32_16x16x32_bf16(
                    fa_l[mf], fb_h[nf], acc[mf][nf], 0, 0, 0);
    }

    // ---- epilogue
    float bv[4], ev[4];
#pragma unroll
    for (int nf = 0; nf < 4; ++nf) {
        int col = n0 + nf * 16 + lr;
        bv[nf] = bias[col];
        ev[nf] = (EPI == 2) ? extra[col] : 0.f;
    }
#pragma unroll
    for (int mf = 0; mf < 4; ++mf)
#pragma unroll
        for (int nf = 0; nf < 4; ++nf) {
            int col = n0 + nf * 16 + lr;
#pragma unroll
            for (int r = 0; r < 4; ++r) {
                int mrow = m0 + mf * 16 + kg * 4 + r;
                float v = acc[mf][nf][r] + bv[nf];
                if (EPI == 1) v = v / (1.f + expf(-v));            // silu
                if (EPI == 2) {                                    // softplus(extra+v)
                    float t2 = ev[nf] + v;
                    v = fmaxf(t2, 0.f) + log1pf(expf(-fabsf(t2)));
                }
                C[(size_t)mrow * N + col] = v;
            }
        }
}

// ---------------------------------------------------------------------------
// depthwise causal conv (K=4) + bias + silu.
// Outputs: a fp32 (for bm/scans), ah/al bf16x2 (for delta-GEMM),
// p=a*g split ph/pl (for output-GEMM), trim = a[...,1:] (final output).
// ---------------------------------------------------------------------------
__global__ __launch_bounds__(256) void conv_k(
    const float* __restrict__ apre, const float* __restrict__ cw,
    const float* __restrict__ cb, const float* __restrict__ g,
    float* __restrict__ aout,
    unsigned short* __restrict__ ah, unsigned short* __restrict__ al,
    unsigned short* __restrict__ ph, unsigned short* __restrict__ pl,
    float* __restrict__ trim)
{
    int idx = blockIdx.x * 256 + threadIdx.x;          // (b*L + t)*H + d
    int d  = idx % H_DIM;
    int bt = idx / H_DIM;
    int t  = bt % LSEQ;

    float4 w = *reinterpret_cast<const float4*>(cw + (size_t)d * KW);
    float acc = cb[d];
    if (t >= KW - 1) {
        const float* base = apre + (size_t)(bt - 3) * H_DIM + d;
        acc += base[0] * w.x;
        acc += base[H_DIM] * w.y;
        acc += base[2 * H_DIM] * w.z;
        acc += base[3 * H_DIM] * w.w;
    } else {
        const float* wp = reinterpret_cast<const float*>(&w);
#pragma unroll
        for (int j = 0; j < KW; ++j) {
            int tt = t + j - (KW - 1);
            if (tt >= 0) acc += apre[(size_t)(bt + j - 3) * H_DIM + d] * wp[j];
        }
    }
    float sv = acc / (1.f + expf(-acc));               // silu
    aout[idx] = sv;
    short h = f2bf(sv);
    ah[idx] = (unsigned short)h;
    al[idx] = (unsigned short)f2bf(sv - bf2f(h));
    float pv = sv * g[idx];
    short hp = f2bf(pv);
    ph[idx] = (unsigned short)hp;
    pl[idx] = (unsigned short)f2bf(pv - bf2f(hp));
    if (d >= 1)
        __builtin_nontemporal_store(sv, &trim[(size_t)bt * (H_DIM - 1) + d - 1]);
}

// ---------------------------------------------------------------------------
// Bm = a @ WB + bB   (skinny N=16)
// ---------------------------------------------------------------------------
__global__ __launch_bounds__(256) void bm_k(
    const float* __restrict__ a, const float* __restrict__ WB,
    const float* __restrict__ bB, float* __restrict__ Bm)
{
    int g = blockIdx.x * 256 + threadIdx.x;            // row*16 + n
    int row = g >> 4, n = g & 15;
    const float* ar = a + (size_t)row * H_DIM;
    float a0 = 0.f, a1 = 0.f, a2 = 0.f, a3 = 0.f;
    for (int k = 0; k < H_DIM; k += 4) {
        a0 = fmaf(ar[k],     WB[(size_t)(k)*DST + n],     a0);
        a1 = fmaf(ar[k + 1], WB[(size_t)(k + 1)*DST + n], a1);
        a2 = fmaf(ar[k + 2], WB[(size_t)(k + 2)*DST + n], a2);
        a3 = fmaf(ar[k + 3], WB[(size_t)(k + 3)*DST + n], a3);
    }
    Bm[g] = bB[n] + ((a0 + a1) + (a2 + a3));
}

// ---------------------------------------------------------------------------
// chunked selective scan:  h_t = (e^{-A} * delta_t) * h_{t-1} + Bm_t*delta_t*a_t
// Intermediates hend/P/Hinit laid out [(b*CCH + c)*HS + ds] (coalesced in ds).
// ---------------------------------------------------------------------------
__global__ __launch_bounds__(256) void scan_a(
    const float* __restrict__ delta, const float* __restrict__ a,
    const float* __restrict__ Bm, const float* __restrict__ A,
    float* __restrict__ hend, float* __restrict__ Pout)
{
    int gtid = blockIdx.x * 256 + threadIdx.x;         // B*CCH*HS
    int ds = gtid % HS;
    int bc = gtid / HS;
    int c = bc % CCH, b = bc / CCH;
    int d = ds >> 4, s = ds & 15;

    float eA = expf(-A[ds]);
    float h = 0.f, P = 1.f;
    int bt0 = b * LSEQ + c * CLEN;
#pragma unroll 4
    for (int i = 0; i < CLEN; ++i) {
        int bt = bt0 + i;
        size_t ix = (size_t)bt * H_DIM + d;
        float dl = delta[ix];
        float av = a[ix];
        float bm = Bm[(size_t)bt * DST + s];
        float at = eA * dl;
        h = fmaf(at, h, bm * dl * av);
        P *= at;
    }
    size_t o = ((size_t)b * CCH + c) * HS + ds;
    hend[o] = h;
    Pout[o] = P;
}

__global__ __launch_bounds__(256) void scan_b(
    const float* __restrict__ hend, const float* __restrict__ P,
    float* __restrict__ Hinit)
{
    int gtid = blockIdx.x * 256 + threadIdx.x;         // B*HS
    int ds = gtid % HS;
    int b  = gtid / HS;
    float Hc = 0.f;
    for (int c = 0; c < CCH; ++c) {
        size_t o = ((size_t)b * CCH + c) * HS + ds;
        Hinit[o] = Hc;
        Hc = hend[o] + P[o] * Hc;
    }
}

__global__ __launch_bounds__(256) void scan_c(
    const float* __restrict__ delta, const float* __restrict__ a,
    const float* __restrict__ Bm, const float* __restrict__ A,
    const float* __restrict__ Hinit, float* __restrict__ hid)
{
    int gtid = blockIdx.x * 256 + threadIdx.x;
    int ds = gtid % HS;
    int bc = gtid / HS;
    int c = bc % CCH, b = bc / CCH;
    int d = ds >> 4, s = ds & 15;

    float eA = expf(-A[ds]);
    float h = Hinit[((size_t)b * CCH + c) * HS + ds];
    int bt0 = b * LSEQ + c * CLEN;
#pragma unroll 4
    for (int i = 0; i < CLEN; ++i) {
        int bt = bt0 + i;
        size_t ix = (size_t)bt * H_DIM + d;
        float dl = delta[ix];
        float av = a[ix];
        float bm = Bm[(size_t)bt * DST + s];
        float at = eA * dl;
        h = fmaf(at, h, bm * dl * av);
        // hid is written once, never re-read on device: stream past the caches
        __builtin_nontemporal_store(h, &hid[(size_t)bt * HS + ds]);
    }
}

// ---------------------------------------------------------------------------
extern "C" void kernel_launch(void* const* d_in, const int* in_sizes, int n_in,
                              void* d_out, int out_size, void* d_ws, size_t ws_size,
                              hipStream_t stream)
{
    const float* x      = (const float*)d_in[0];
    const float* W1     = (const float*)d_in[1];
    const float* b1     = (const float*)d_in[2];
    const float* W2     = (const float*)d_in[3];
    const float* b2     = (const float*)d_in[4];
    const float* conv_w = (const float*)d_in[5];
    const float* conv_b = (const float*)d_in[6];
    const float* Wf     = (const float*)d_in[7];
    const float* bf     = (const float*)d_in[8];
    const float* A      = (const float*)d_in[9];
    const float* WB     = (const float*)d_in[10];
    const float* bB     = (const float*)d_in[11];
    // d_in[12] = WC, d_in[13] = bC : unused by the reference's returned outputs
    const float* WD     = (const float*)d_in[14];
    const float* bD     = (const float*)d_in[15];
    const float* Dvec   = (const float*)d_in[16];

    float* out = (float*)d_out;
    // output layout: [output 4096*768][hid 4096*24576][trim 4096*1535]
    constexpr size_t OUT_HID  = (size_t)MROWS * DIM;
    constexpr size_t OUT_TRIM = OUT_HID + (size_t)MROWS * HS;
    float* out_y    = out;
    float* out_hid  = out + OUT_HID;
    float* out_trim = out + OUT_TRIM;

    // scratch inside the (not-yet-written) hid region of d_out (402 MB);
    // everything here is dead before scan_c overwrites hid.
    constexpr size_t MH = (size_t)MROWS * H_DIM;                   // 6,291,456
    constexpr size_t MD = (size_t)MROWS * DIM;                     // 3,145,728
    float* a_pre = out_hid;                                        // [MH] fp32
    float* g     = out_hid + MH;                                   // [MH] fp32
    unsigned short* wsp = (unsigned short*)(out_hid + 2 * MH);
    constexpr size_t WSMALL = (size_t)H_DIM * DIM;                 // 1,179,648
    constexpr size_t WBIG   = (size_t)H_DIM * H_DIM;               // 2,359,296
    unsigned short* W1h = wsp;            unsigned short* W1l = W1h + WSMALL;
    unsigned short* W2h = W1l + WSMALL;   unsigned short* W2l = W2h + WSMALL;
    unsigned short* WDh = W2l + WSMALL;   unsigned short* WDl = WDh + WBIG;
    unsigned short* Wfh = WDl + WBIG;     unsigned short* Wfl = Wfh + WSMALL;
    unsigned short* xh  = Wfl + WSMALL;   unsigned short* xl  = xh + MD;
    unsigned short* ah  = xl + MD;        unsigned short* al  = ah + MH;
    unsigned short* ph  = al + MH;        unsigned short* pl  = ph + MH;
    // total scratch ~137 MB < 402 MB hid region.

    // workspace layout (floats): a(6.29M) delta(6.29M) Bm(64K) hend/P/Hinit
    float* ws      = (float*)d_ws;
    float* a_ws    = ws;
    float* delta   = a_ws  + MH;
    float* Bm      = delta + MH;
    float* hend    = Bm    + (size_t)MROWS * DST;
    float* Pprod   = hend  + (size_t)B_SZ * HS * CCH;
    float* Hinit   = Pprod + (size_t)B_SZ * HS * CCH;

    dim3 blk(256);
    dim3 wblk(64);

    // 0) operand prep: weight transpose+split, x split
    wsplit_k<<<dim3(DIM / 32, H_DIM / 32), blk, 0, stream>>>(W1, W1h, W1l, DIM, H_DIM);
    wsplit_k<<<dim3(DIM / 32, H_DIM / 32), blk, 0, stream>>>(W2, W2h, W2l, DIM, H_DIM);
    wsplit_k<<<dim3(H_DIM / 32, H_DIM / 32), blk, 0, stream>>>(WD, WDh, WDl, H_DIM, H_DIM);
    wsplit_k<<<dim3(H_DIM / 32, DIM / 32), blk, 0, stream>>>(Wf, Wfh, Wfl, H_DIM, DIM);
    xsplit_k<<<(unsigned)((MD / 8 + 255) / 256), blk, 0, stream>>>(x, xh, xl, MD / 8);

    // 1) a_pre = x@W1 + b1            [4096 x 1536, K=768]  grid 24x64 waves
    gemm_reg<0><<<dim3(H_DIM / 64, MROWS / 64), wblk, 0, stream>>>(
        xh, xl, W1h, W1l, b1, nullptr, a_pre, MROWS, H_DIM, DIM);
    // 2) g = silu(x@W2 + b2)
    gemm_reg<1><<<dim3(H_DIM / 64, MROWS / 64), wblk, 0, stream>>>(
        xh, xl, W2h, W2l, b2, nullptr, g, MROWS, H_DIM, DIM);
    // 3) conv -> a (fp32 + bf16x2) and p = a*g (bf16x2), trim output
    conv_k<<<(MROWS * H_DIM) / 256, blk, 0, stream>>>(
        a_pre, conv_w, conv_b, g, a_ws, ah, al, ph, pl, out_trim);
    // 4) delta = softplus(Dvec + a@WD + bD)   [4096 x 1536, K=1536]
    gemm_reg<2><<<dim3(H_DIM / 64, MROWS / 64), wblk, 0, stream>>>(
        ah, al, WDh, WDl, bD, Dvec, delta, MROWS, H_DIM, H_DIM);
    // 5) Bm = a@WB + bB
    bm_k<<<(MROWS * DST) / 256, blk, 0, stream>>>(a_ws, WB, bB, Bm);
    // 6) output = (a*g)@Wf + bf  [4096 x 768, K=1536]  grid 12x64 waves
    gemm_reg<0><<<dim3(DIM / 64, MROWS / 64), wblk, 0, stream>>>(
        ph, pl, Wfh, Wfl, bf, nullptr, out_y, MROWS, DIM, H_DIM);
    // 7-9) chunked selective scan -> hid
    scan_a<<<(B_SZ * CCH * HS) / 256, blk, 0, stream>>>(delta, a_ws, Bm, A, hend, Pprod);
    scan_b<<<(B_SZ * HS) / 256, blk, 0, stream>>>(hend, Pprod, Hinit);
    scan_c<<<(B_SZ * CCH * HS) / 256, blk, 0, stream>>>(delta, a_ws, Bm, A, Hinit, out_hid);
}